// Round 1
// baseline (475.229 us; speedup 1.0000x reference)
//
#include <hip/hip_runtime.h>
#include <stdint.h>

// Problem constants
#define Bsz 1024
#define Tn  20
#define Hn  768
#define G4n 3072   // 4*H

// Workspace layout (floats):
//  [0..31]      Sh[t]
//  [32..63]     Sev[t]
//  [64..575]    part[256]: uint64 {token<<32 | float bits}
//  [576..639]   bcast (legacy, zeroed, unused)
//  [640..]      rowsum[20][3072]
//  [+61440]     biassum[20][3072]
//  [+61440]     c0 handoff [1024][768]
//  then bf16 planes for the t=0 GEMM (ushort):
//   evh  [1024][768], evl  [1024][768]      (ev[:,0,:] hi/lo)
//   wh   [2304][768], wl   [2304][768]      (whh[0] gates {i,g,o} hi/lo)
#define WS_SH    0
#define WS_SEV   32
#define WS_PART  64
#define WS_BCAST 576
#define WS_RS    640
#define WS_BS    62080
#define WS_C     123520
#define WS_EVH   909952
#define WS_EVL   1303168
#define WS_WH    1696384
#define WS_WL    2581120
// total = 3,465,856 floats = 13.9 MB

// k_conv blocks: 512 ev (2 rows each) + 1152 whh (2 plane-rows each) + 3 zero
#define NBC_EV   512
#define NBC_W    1152
#define NBC_Z    3
#define NBC_TOT  (NBC_EV + NBC_W + NBC_Z)

// k_pre blocks
#define NB_GEMM   768    // 16 bt x 48 kt, 64x16 tile x 3 gates
#define NB_ROWSUM 1824   // 19*3072 rows / (4 waves * 8 rows)
#define NB_SEV    608    // 19*1024 rows / (4 waves * 8 rows)
#define NB_BIAS   60     // 61440 floats / (256 thr * float4)
#define NB_TOTAL  (NB_GEMM + NB_ROWSUM + NB_SEV + NB_BIAS)

typedef float  floatx4 __attribute__((ext_vector_type(4)));
typedef short  bfrag8  __attribute__((ext_vector_type(8)));

__device__ __forceinline__ float wave_reduce(float v){
#pragma unroll
    for (int o = 32; o > 0; o >>= 1) v += __shfl_down(v, o, 64);
    return v;
}
__device__ __forceinline__ float sigf(float x){ return 1.0f/(1.0f+__expf(-x)); }
__device__ __forceinline__ float tanhfast(float x){ return 2.0f/(1.0f+__expf(-2.0f*x)) - 1.0f; }
__device__ __forceinline__ unsigned short f2bf(float f){
    uint32_t u = __float_as_uint(f);
    return (unsigned short)((u + 0x7fffu + ((u>>16)&1u)) >> 16);
}
__device__ __forceinline__ float bf2f(unsigned short h){ return __uint_as_float(((uint32_t)h)<<16); }
__device__ __forceinline__ uint64_t pack_tv(unsigned t, float v){
    return ((uint64_t)t << 32) | (uint64_t)__float_as_uint(v);
}

// ---------------- K0: one-time bf16 hi/lo plane conversion + slot zeroing ----------------
__global__ __launch_bounds__(256) void k_conv(
    const float* __restrict__ ev, const float* __restrict__ whh,
    float* __restrict__ ws)
{
    int bid = blockIdx.x, tid = threadIdx.x;
    if (bid < NBC_EV + NBC_W) {
        if (tid >= 192) return;
        int r = tid / 96;                 // 0 or 1: which of the 2 rows
        int i = (tid - r*96) * 8;         // 0..760, 8 elems/thread
        const float* src;
        unsigned short *dh, *dl;
        if (bid < NBC_EV) {
            int b = bid*2 + r;            // ev row (t=0 slice)
            src = ev + (size_t)b*(Tn*Hn) + i;
            dh = (unsigned short*)(ws + WS_EVH) + (size_t)b*Hn + i;
            dl = (unsigned short*)(ws + WS_EVL) + (size_t)b*Hn + i;
        } else {
            int p = (bid - NBC_EV)*2 + r;           // plane row 0..2303
            int gsel = p / Hn;                      // 0,1,2
            int ga = (gsel==0) ? 0 : (gsel==1 ? 2 : 3);  // gates i,g,o
            int j = ga*Hn + (p - gsel*Hn);          // whh[0] row
            src = whh + (size_t)j*Hn + i;
            dh = (unsigned short*)(ws + WS_WH) + (size_t)p*Hn + i;
            dl = (unsigned short*)(ws + WS_WL) + (size_t)p*Hn + i;
        }
        float4 v0 = *(const float4*)src;
        float4 v1 = *(const float4*)(src+4);
        float f[8] = {v0.x,v0.y,v0.z,v0.w,v1.x,v1.y,v1.z,v1.w};
        bfrag8 hv, lv;
#pragma unroll
        for (int q = 0; q < 8; ++q) {
            unsigned short hb = f2bf(f[q]);
            hv[q] = (short)hb;
            lv[q] = (short)f2bf(f[q] - bf2f(hb));
        }
        *(bfrag8*)dh = hv;
        *(bfrag8*)dl = lv;
    } else {
        int idx = (bid - NBC_EV - NBC_W)*256 + tid;
        if (idx < 640) ws[idx] = 0.0f;
    }
}

// ---------------- K1 (merged): t=0 GEMM + rowsums + Sev + biassums ----------------
__global__ __launch_bounds__(256) void k_pre(
    const float* __restrict__ price, const float* __restrict__ ev,
    const float* __restrict__ wih,   const float* __restrict__ whh,
    const float* __restrict__ bih,   const float* __restrict__ bhh,
    float* __restrict__ ws)
{
    __shared__ float redk[4];
    int blk = blockIdx.x, tid = threadIdx.x;
    int lane = tid & 63, wid = tid >> 6;

    if (blk < NB_GEMM) {
        // ----- t=0 GEMM, 3 live gates {i,g,o}, bf16x3, LDS-free fragment-direct -----
        float* Sh   = ws + WS_SH;
        float* cbuf = ws + WS_C;
        int bt = blk / 48, kt = blk % 48;
        int b0 = bt*64, k0 = kt*16;
        int w = wid, q = lane >> 4, col = lane & 15;

        const unsigned short* evh = (const unsigned short*)(ws + WS_EVH);
        const unsigned short* evl = (const unsigned short*)(ws + WS_EVL);
        const unsigned short* wh  = (const unsigned short*)(ws + WS_WH);
        const unsigned short* wl  = (const unsigned short*)(ws + WS_WL);

        int arow = b0 + w*16 + col;
        const unsigned short* pah = evh + (size_t)arow*Hn + q*8;
        const unsigned short* pal = evl + (size_t)arow*Hn + q*8;
        int br0 = 0*Hn + k0 + col;   // gate i plane row
        int br1 = 1*Hn + k0 + col;   // gate g plane row
        int br2 = 2*Hn + k0 + col;   // gate o plane row
        const unsigned short* pbh0 = wh + (size_t)br0*Hn + q*8;
        const unsigned short* pbl0 = wl + (size_t)br0*Hn + q*8;
        const unsigned short* pbh1 = wh + (size_t)br1*Hn + q*8;
        const unsigned short* pbl1 = wl + (size_t)br1*Hn + q*8;
        const unsigned short* pbh2 = wh + (size_t)br2*Hn + q*8;
        const unsigned short* pbl2 = wl + (size_t)br2*Hn + q*8;

        floatx4 acc0 = (floatx4){0.f,0.f,0.f,0.f};
        floatx4 acc1 = (floatx4){0.f,0.f,0.f,0.f};
        floatx4 acc2 = (floatx4){0.f,0.f,0.f,0.f};

#pragma unroll 4
        for (int kk = 0; kk < Hn; kk += 32) {
            bfrag8 ah = *(const bfrag8*)(pah + kk);
            bfrag8 al = *(const bfrag8*)(pal + kk);
            bfrag8 b0h = *(const bfrag8*)(pbh0 + kk);
            bfrag8 b0l = *(const bfrag8*)(pbl0 + kk);
            acc0 = __builtin_amdgcn_mfma_f32_16x16x32_bf16(ah, b0h, acc0, 0,0,0);
            acc0 = __builtin_amdgcn_mfma_f32_16x16x32_bf16(ah, b0l, acc0, 0,0,0);
            acc0 = __builtin_amdgcn_mfma_f32_16x16x32_bf16(al, b0h, acc0, 0,0,0);
            bfrag8 b1h = *(const bfrag8*)(pbh1 + kk);
            bfrag8 b1l = *(const bfrag8*)(pbl1 + kk);
            acc1 = __builtin_amdgcn_mfma_f32_16x16x32_bf16(ah, b1h, acc1, 0,0,0);
            acc1 = __builtin_amdgcn_mfma_f32_16x16x32_bf16(ah, b1l, acc1, 0,0,0);
            acc1 = __builtin_amdgcn_mfma_f32_16x16x32_bf16(al, b1h, acc1, 0,0,0);
            bfrag8 b2h = *(const bfrag8*)(pbh2 + kk);
            bfrag8 b2l = *(const bfrag8*)(pbl2 + kk);
            acc2 = __builtin_amdgcn_mfma_f32_16x16x32_bf16(ah, b2h, acc2, 0,0,0);
            acc2 = __builtin_amdgcn_mfma_f32_16x16x32_bf16(ah, b2l, acc2, 0,0,0);
            acc2 = __builtin_amdgcn_mfma_f32_16x16x32_bf16(al, b2h, acc2, 0,0,0);
        }

        float hsum = 0.f;
#pragma unroll
        for (int r = 0; r < 4; ++r) {
            int b = b0 + w*16 + q*4 + r;
            float4 xv = *(const float4*)(price + (size_t)b*(Tn*4));
            int j0 = 0*Hn + k0 + col;
            int j1 = 2*Hn + k0 + col;
            int j2 = 3*Hn + k0 + col;
            float4 w0 = *(const float4*)(wih + (size_t)j0*4);
            float4 w1 = *(const float4*)(wih + (size_t)j1*4);
            float4 w2 = *(const float4*)(wih + (size_t)j2*4);
            float gi = acc0[r] + xv.x*w0.x + xv.y*w0.y + xv.z*w0.z + xv.w*w0.w + bih[j0] + bhh[j0];
            float gg = acc1[r] + xv.x*w1.x + xv.y*w1.y + xv.z*w1.z + xv.w*w1.w + bih[j1] + bhh[j1];
            float go = acc2[r] + xv.x*w2.x + xv.y*w2.y + xv.z*w2.z + xv.w*w2.w + bih[j2] + bhh[j2];
            float c0 = sigf(gi) * tanhfast(gg);
            float h0 = sigf(go) * tanhfast(c0);
            cbuf[(size_t)b*Hn + k0 + col] = c0;
            hsum += h0;
        }
        hsum = wave_reduce(hsum);
        if (lane == 0) redk[w] = hsum;
        __syncthreads();
        if (tid == 0) atomicAdd(&Sh[0], redk[0]+redk[1]+redk[2]+redk[3]);
        return;
    }

    blk -= NB_GEMM;
    if (blk < NB_ROWSUM) {                   // whh row sums, t=1..19, 8 rows/wave
        int gw = blk*4 + wid;
        int t  = 1 + gw/384;
        int j0 = (gw - (t-1)*384)*8;
        const float* base = whh + ((size_t)t*G4n + j0)*Hn + (size_t)lane*4;
        float s[8];
#pragma unroll
        for (int r = 0; r < 8; ++r) {
            float4 v0 = *(const float4*)(base + (size_t)r*Hn);
            float4 v1 = *(const float4*)(base + (size_t)r*Hn + 256);
            float4 v2 = *(const float4*)(base + (size_t)r*Hn + 512);
            s[r] = (v0.x+v0.y+v0.z+v0.w) + (v1.x+v1.y+v1.z+v1.w) + (v2.x+v2.y+v2.z+v2.w);
        }
        float* rowsum = ws + WS_RS;
#pragma unroll
        for (int r = 0; r < 8; ++r) {
            float rs = wave_reduce(s[r]);
            if (lane == 0) rowsum[(size_t)t*G4n + j0 + r] = rs;
        }
        return;
    }

    blk -= NB_ROWSUM;
    if (blk < NB_SEV) {                      // Sev[t] partials, 8 b-rows/wave
        int gw = blk*4 + wid;
        int t   = 1 + gw/128;
        int b0s = (gw - (t-1)*128)*8;
        float s = 0.f;
#pragma unroll
        for (int r = 0; r < 8; ++r) {
            const float* base = ev + ((size_t)(b0s+r)*Tn + t)*Hn + (size_t)lane*4;
            float4 v0 = *(const float4*)(base);
            float4 v1 = *(const float4*)(base + 256);
            float4 v2 = *(const float4*)(base + 512);
            s += (v0.x+v0.y+v0.z+v0.w) + (v1.x+v1.y+v1.z+v1.w) + (v2.x+v2.y+v2.z+v2.w);
        }
        s = wave_reduce(s);
        if (lane == 0) atomicAdd(ws + WS_SEV + t, s);
        return;
    }

    blk -= NB_SEV;
    {                                        // biassum, float4
        int idx = blk*256 + tid;             // 0..15359
        float4 a = *(const float4*)(bih + (size_t)idx*4);
        float4 b = *(const float4*)(bhh + (size_t)idx*4);
        float4 r4; r4.x=a.x+b.x; r4.y=a.y+b.y; r4.z=a.z+b.z; r4.w=a.w+b.w;
        *(float4*)(ws + WS_BS + (size_t)idx*4) = r4;
    }
}

// ---------------- K2: persistent fused recurrence, t=1..19 ----------------
// 256 blocks x 768 threads. Single-hop all-to-all exchange: every block
// publishes its token-packed partial, every block polls all 256 slots and
// reduces locally. No hub, no bcast hop. Publish happens BEFORE the
// coefficient preload so propagation hides under the wih/rowsum loads.
__global__ __launch_bounds__(768) void k_steps(
    const float* __restrict__ price, const float* __restrict__ wih,
    const float* __restrict__ fcw,   const float* __restrict__ fcb,
    float* __restrict__ ws, float* __restrict__ out)
{
    __shared__ float pr[4][80];
    __shared__ float red[12];
    __shared__ float redP[4];
    __shared__ float redF[4][12];

    float* Sh  = ws + WS_SH;
    float* Sev = ws + WS_SEV;
    uint64_t* part = (uint64_t*)(ws + WS_PART);
    const float* rowsum  = ws + WS_RS;
    const float* biassum = ws + WS_BS;
    float* cbuf = ws + WS_C;

    int blk = blockIdx.x, tid = threadIdx.x;
    int lane = tid & 63, wid = tid >> 6;
    int k = tid;

    if (tid < 320) {
        int e = tid / 80, r = tid - e*80;
        pr[e][r] = price[(size_t)(blk + 256*e)*(Tn*4) + r];
    }

    float c[4];
#pragma unroll
    for (int e = 0; e < 4; ++e)
        c[e] = cbuf[(size_t)(blk + 256*e)*Hn + k];

    float fcwk = fcw[k];
    float fcb0 = fcb[0];
    float sh0  = Sh[0];

    __syncthreads();

    float hsum_prev = 0.f;
    float vout[4] = {0.f,0.f,0.f,0.f};

    for (int t = 1; t < Tn; ++t) {
        // ---- publish previous step's block partial (token t-1) ----
        if (t >= 2) {
            float v = wave_reduce(hsum_prev);
            if (lane == 0) red[wid] = v;
            __syncthreads();
            if (tid == 0) {
                float tot = 0.f;
#pragma unroll
                for (int i = 0; i < 12; ++i) tot += red[i];
                __hip_atomic_store(&part[blk], pack_tv((unsigned)(t-1), tot),
                                   __ATOMIC_RELAXED, __HIP_MEMORY_SCOPE_AGENT);
            }
        }

        // ---- preload step-t coefficients + hx-independent gate bases ----
        const float* wih_t = wih + (size_t)t*G4n*4;
        float rsv[4], base[4][4];
#pragma unroll
        for (int g = 0; g < 4; ++g) {
            int j = g*Hn + k;
            float4 wv = *(const float4*)(wih_t + (size_t)j*4);
            rsv[g]   = rowsum[t*G4n + j];
            float bs = biassum[t*G4n + j];
#pragma unroll
            for (int e = 0; e < 4; ++e) {
                base[e][g] = pr[e][t*4+0]*wv.x + pr[e][t*4+1]*wv.y
                           + pr[e][t*4+2]*wv.z + pr[e][t*4+3]*wv.w + bs;
            }
        }
        float sevt = Sev[t];

        // ---- obtain hx_t (all-to-all) ----
        float hx;
        if (t == 1) {
            hx = sevt + sh0;
        } else {
            if (tid < 256) {
                uint64_t u = __hip_atomic_load(&part[tid], __ATOMIC_RELAXED, __HIP_MEMORY_SCOPE_AGENT);
                while ((unsigned)(u >> 32) != (unsigned)(t-1)) {
                    __builtin_amdgcn_s_sleep(1);
                    u = __hip_atomic_load(&part[tid], __ATOMIC_RELAXED, __HIP_MEMORY_SCOPE_AGENT);
                }
                float pv = wave_reduce(__uint_as_float((uint32_t)u));
                if (lane == 0) redP[wid] = pv;
            }
            __syncthreads();
            hx = sevt + (redP[0]+redP[1]+redP[2]+redP[3]);
        }

        // ---- cell update ----
        float hsum = 0.f;
#pragma unroll
        for (int e = 0; e < 4; ++e) {
            float gi = base[e][0] + hx*rsv[0];
            float gf = base[e][1] + hx*rsv[1];
            float gg = base[e][2] + hx*rsv[2];
            float go = base[e][3] + hx*rsv[3];
            float cn = sigf(gf)*c[e] + sigf(gi)*tanhfast(gg);
            c[e] = cn;
            float h = sigf(go)*tanhfast(cn);
            hsum += h;
            if (t == Tn-1) vout[e] = wave_reduce(h * fcwk);
        }
        hsum_prev = hsum;
    }

    // epilogue: out[b] = h19[b,:].fc_w + fc_b
    if (lane == 0) {
#pragma unroll
        for (int e = 0; e < 4; ++e) redF[e][wid] = vout[e];
    }
    __syncthreads();
    if (tid < 4) {
        float tot = 0.f;
#pragma unroll
        for (int i = 0; i < 12; ++i) tot += redF[tid][i];
        out[blk + 256*tid] = tot + fcb0;
    }
}

extern "C" void kernel_launch(void* const* d_in, const int* in_sizes, int n_in,
                              void* d_out, int out_size, void* d_ws, size_t ws_size,
                              hipStream_t stream)
{
    const float* price = (const float*)d_in[0];
    const float* ev    = (const float*)d_in[1];
    const float* wih   = (const float*)d_in[2];
    const float* whh   = (const float*)d_in[3];
    const float* bih   = (const float*)d_in[4];
    const float* bhh   = (const float*)d_in[5];
    const float* fcw   = (const float*)d_in[6];
    const float* fcb   = (const float*)d_in[7];
    float* out = (float*)d_out;
    float* ws  = (float*)d_ws;

    k_conv <<<NBC_TOT, 256, 0, stream>>>(ev, whh, ws);
    k_pre  <<<NB_TOTAL, 256, 0, stream>>>(price, ev, wih, whh, bih, bhh, ws);
    k_steps<<<256, 768, 0, stream>>>(price, wih, fcw, fcb, ws, out);
}

// Round 2
// 428.130 us; speedup vs baseline: 1.1100x; 1.1100x over previous
//
#include <hip/hip_runtime.h>
#include <stdint.h>

// Problem constants
#define Bsz 1024
#define Tn  20
#define Hn  768
#define G4n 3072   // 4*H

// Workspace layout (floats):
//  [0..31]      Sh[t]
//  [32..63]     Sev[t]
//  [64..575]    part[256]: uint64 {token<<32 | float bits}
//  [576..639]   bcast: uint64 {token<<32 | hx bits}
//  [640..]      rowsum[20][3072]
//  [+61440]     biassum[20][3072]
//  [+61440]     c0 handoff [1024][768]
//  then bf16 planes for the t=0 GEMM (ushort), stored in MFMA FRAGMENT ORDER:
//  chunk(rb,kb) = 64 lanes x 8 elems; elem (l,e) = plane[rb*16 + (l&15)][kb*32 + (l>>4)*8 + e]
//   evh  [64 rb][24 kb][512], evl  same      (ev[:,0,:] hi/lo)
//   wh   [144 rb][24 kb][512], wl  same      (whh[0] gates {i,g,o} hi/lo)
#define WS_SH    0
#define WS_SEV   32
#define WS_PART  64
#define WS_BCAST 576
#define WS_RS    640
#define WS_BS    62080
#define WS_C     123520
#define WS_EVH   909952
#define WS_EVL   1303168
#define WS_WH    1696384
#define WS_WL    2581120

// k_conv blocks: 512 ev (2 rows each) + 1152 whh (2 plane-rows each) + 3 zero
#define NBC_EV   512
#define NBC_W    1152
#define NBC_Z    3
#define NBC_TOT  (NBC_EV + NBC_W + NBC_Z)

// k_pre blocks
#define NB_GEMM   768    // 16 bt x 48 kt, 64x16 tile x 3 gates
#define NB_ROWSUM 1824   // 19*3072 rows / (4 waves * 8 rows)
#define NB_SEV    608    // 19*1024 rows / (4 waves * 8 rows)
#define NB_BIAS   60     // 61440 floats / (256 thr * float4)
#define NB_TOTAL  (NB_GEMM + NB_ROWSUM + NB_SEV + NB_BIAS)

typedef float  floatx4 __attribute__((ext_vector_type(4)));
typedef short  bfrag8  __attribute__((ext_vector_type(8)));

__device__ __forceinline__ float wave_reduce(float v){
#pragma unroll
    for (int o = 32; o > 0; o >>= 1) v += __shfl_down(v, o, 64);
    return v;
}
__device__ __forceinline__ float sigf(float x){ return 1.0f/(1.0f+__expf(-x)); }
__device__ __forceinline__ float tanhfast(float x){ return 2.0f/(1.0f+__expf(-2.0f*x)) - 1.0f; }
__device__ __forceinline__ unsigned short f2bf(float f){
    uint32_t u = __float_as_uint(f);
    return (unsigned short)((u + 0x7fffu + ((u>>16)&1u)) >> 16);
}
__device__ __forceinline__ float bf2f(unsigned short h){ return __uint_as_float(((uint32_t)h)<<16); }
__device__ __forceinline__ uint64_t pack_tv(unsigned t, float v){
    return ((uint64_t)t << 32) | (uint64_t)__float_as_uint(v);
}

// ---------------- K0: one-time bf16 hi/lo conversion into fragment-order planes ----------------
__global__ __launch_bounds__(256) void k_conv(
    const float* __restrict__ ev, const float* __restrict__ whh,
    float* __restrict__ ws)
{
    int bid = blockIdx.x, tid = threadIdx.x;
    if (bid < NBC_EV + NBC_W) {
        if (tid >= 192) return;
        int r = tid / 96;                 // which of the 2 rows this block covers
        int i = (tid - r*96) * 8;         // element offset 0..760
        const float* src;
        unsigned short *dh, *dl;
        int prow;                         // plane row index
        if (bid < NBC_EV) {
            prow = bid*2 + r;             // ev row b (t=0 slice)
            src = ev + (size_t)prow*(Tn*Hn) + i;
            dh = (unsigned short*)(ws + WS_EVH);
            dl = (unsigned short*)(ws + WS_EVL);
        } else {
            int p = (bid - NBC_EV)*2 + r;           // plane row 0..2303
            int gsel = p / Hn;                      // 0,1,2
            int ga = (gsel==0) ? 0 : (gsel==1 ? 2 : 3);  // gates i,g,o
            int j = ga*Hn + (p - gsel*Hn);          // whh[0] row
            prow = p;
            src = whh + (size_t)j*Hn + i;
            dh = (unsigned short*)(ws + WS_WH);
            dl = (unsigned short*)(ws + WS_WL);
        }
        // fragment-order destination: chunk(rb,kb), lane q*16+col, elem e
        int rb = prow >> 4, col = prow & 15;
        int kb = i >> 5, q = (i >> 3) & 3;
        size_t base = (((size_t)(rb*24 + kb))*64 + q*16 + col) * 8;

        float4 v0 = *(const float4*)src;
        float4 v1 = *(const float4*)(src+4);
        float f[8] = {v0.x,v0.y,v0.z,v0.w,v1.x,v1.y,v1.z,v1.w};
        bfrag8 hv, lv;
#pragma unroll
        for (int qq = 0; qq < 8; ++qq) {
            unsigned short hb = f2bf(f[qq]);
            hv[qq] = (short)hb;
            lv[qq] = (short)f2bf(f[qq] - bf2f(hb));
        }
        *(bfrag8*)(dh + base) = hv;
        *(bfrag8*)(dl + base) = lv;
    } else {
        int idx = (bid - NBC_EV - NBC_W)*256 + tid;
        if (idx < 640) ws[idx] = 0.0f;
    }
}

// ---------------- K1 (merged): t=0 GEMM + rowsums + Sev + biassums ----------------
__global__ __launch_bounds__(256) void k_pre(
    const float* __restrict__ price, const float* __restrict__ ev,
    const float* __restrict__ wih,   const float* __restrict__ whh,
    const float* __restrict__ bih,   const float* __restrict__ bhh,
    float* __restrict__ ws)
{
    __shared__ float redk[4];
    int blk = blockIdx.x, tid = threadIdx.x;
    int lane = tid & 63, wid = tid >> 6;

    if (blk < NB_GEMM) {
        // ----- t=0 GEMM, 3 live gates {i,g,o}, bf16x3, fragment-order coalesced loads -----
        float* Sh   = ws + WS_SH;
        float* cbuf = ws + WS_C;
        int bt = blk / 48, kt = blk % 48;
        int b0 = bt*64, k0 = kt*16;
        int w = wid, q = lane >> 4, col = lane & 15;

        const unsigned short* evh = (const unsigned short*)(ws + WS_EVH);
        const unsigned short* evl = (const unsigned short*)(ws + WS_EVL);
        const unsigned short* wh  = (const unsigned short*)(ws + WS_WH);
        const unsigned short* wl  = (const unsigned short*)(ws + WS_WL);

        int rb_a = bt*4 + w;
        const unsigned short* pah = evh + (size_t)rb_a*24*512 + (size_t)lane*8;
        const unsigned short* pal = evl + (size_t)rb_a*24*512 + (size_t)lane*8;
        const unsigned short* pb0h = wh + (size_t)(  0 + kt)*24*512 + (size_t)lane*8; // gate i
        const unsigned short* pb0l = wl + (size_t)(  0 + kt)*24*512 + (size_t)lane*8;
        const unsigned short* pb1h = wh + (size_t)( 48 + kt)*24*512 + (size_t)lane*8; // gate g
        const unsigned short* pb1l = wl + (size_t)( 48 + kt)*24*512 + (size_t)lane*8;
        const unsigned short* pb2h = wh + (size_t)( 96 + kt)*24*512 + (size_t)lane*8; // gate o
        const unsigned short* pb2l = wl + (size_t)( 96 + kt)*24*512 + (size_t)lane*8;

        floatx4 acc0 = (floatx4){0.f,0.f,0.f,0.f};
        floatx4 acc1 = (floatx4){0.f,0.f,0.f,0.f};
        floatx4 acc2 = (floatx4){0.f,0.f,0.f,0.f};

#pragma unroll 4
        for (int kb = 0; kb < 24; ++kb) {
            int off = kb*512;
            bfrag8 ah  = *(const bfrag8*)(pah  + off);
            bfrag8 al  = *(const bfrag8*)(pal  + off);
            bfrag8 b0h = *(const bfrag8*)(pb0h + off);
            bfrag8 b0l = *(const bfrag8*)(pb0l + off);
            acc0 = __builtin_amdgcn_mfma_f32_16x16x32_bf16(ah, b0h, acc0, 0,0,0);
            acc0 = __builtin_amdgcn_mfma_f32_16x16x32_bf16(ah, b0l, acc0, 0,0,0);
            acc0 = __builtin_amdgcn_mfma_f32_16x16x32_bf16(al, b0h, acc0, 0,0,0);
            bfrag8 b1h = *(const bfrag8*)(pb1h + off);
            bfrag8 b1l = *(const bfrag8*)(pb1l + off);
            acc1 = __builtin_amdgcn_mfma_f32_16x16x32_bf16(ah, b1h, acc1, 0,0,0);
            acc1 = __builtin_amdgcn_mfma_f32_16x16x32_bf16(ah, b1l, acc1, 0,0,0);
            acc1 = __builtin_amdgcn_mfma_f32_16x16x32_bf16(al, b1h, acc1, 0,0,0);
            bfrag8 b2h = *(const bfrag8*)(pb2h + off);
            bfrag8 b2l = *(const bfrag8*)(pb2l + off);
            acc2 = __builtin_amdgcn_mfma_f32_16x16x32_bf16(ah, b2h, acc2, 0,0,0);
            acc2 = __builtin_amdgcn_mfma_f32_16x16x32_bf16(ah, b2l, acc2, 0,0,0);
            acc2 = __builtin_amdgcn_mfma_f32_16x16x32_bf16(al, b2h, acc2, 0,0,0);
        }

        // epilogue (weights/bias hoisted out of the r loop — r-independent)
        int j0 = 0*Hn + k0 + col;
        int j1 = 2*Hn + k0 + col;
        int j2 = 3*Hn + k0 + col;
        float4 w0 = *(const float4*)(wih + (size_t)j0*4);
        float4 w1 = *(const float4*)(wih + (size_t)j1*4);
        float4 w2 = *(const float4*)(wih + (size_t)j2*4);
        float bb0 = bih[j0] + bhh[j0];
        float bb1 = bih[j1] + bhh[j1];
        float bb2 = bih[j2] + bhh[j2];

        float hsum = 0.f;
#pragma unroll
        for (int r = 0; r < 4; ++r) {
            int b = b0 + w*16 + q*4 + r;
            float4 xv = *(const float4*)(price + (size_t)b*(Tn*4));
            float gi = acc0[r] + xv.x*w0.x + xv.y*w0.y + xv.z*w0.z + xv.w*w0.w + bb0;
            float gg = acc1[r] + xv.x*w1.x + xv.y*w1.y + xv.z*w1.z + xv.w*w1.w + bb1;
            float go = acc2[r] + xv.x*w2.x + xv.y*w2.y + xv.z*w2.z + xv.w*w2.w + bb2;
            float c0 = sigf(gi) * tanhfast(gg);
            float h0 = sigf(go) * tanhfast(c0);
            cbuf[(size_t)b*Hn + k0 + col] = c0;
            hsum += h0;
        }
        hsum = wave_reduce(hsum);
        if (lane == 0) redk[w] = hsum;
        __syncthreads();
        if (tid == 0) atomicAdd(&Sh[0], redk[0]+redk[1]+redk[2]+redk[3]);
        return;
    }

    blk -= NB_GEMM;
    if (blk < NB_ROWSUM) {                   // whh row sums, t=1..19, 8 rows/wave
        int gw = blk*4 + wid;
        int t  = 1 + gw/384;
        int j0 = (gw - (t-1)*384)*8;
        const float* base = whh + ((size_t)t*G4n + j0)*Hn + (size_t)lane*4;
        float s[8];
#pragma unroll
        for (int r = 0; r < 8; ++r) {
            float4 v0 = *(const float4*)(base + (size_t)r*Hn);
            float4 v1 = *(const float4*)(base + (size_t)r*Hn + 256);
            float4 v2 = *(const float4*)(base + (size_t)r*Hn + 512);
            s[r] = (v0.x+v0.y+v0.z+v0.w) + (v1.x+v1.y+v1.z+v1.w) + (v2.x+v2.y+v2.z+v2.w);
        }
        float* rowsum = ws + WS_RS;
#pragma unroll
        for (int r = 0; r < 8; ++r) {
            float rs = wave_reduce(s[r]);
            if (lane == 0) rowsum[(size_t)t*G4n + j0 + r] = rs;
        }
        return;
    }

    blk -= NB_ROWSUM;
    if (blk < NB_SEV) {                      // Sev[t] partials, 8 b-rows/wave
        int gw = blk*4 + wid;
        int t   = 1 + gw/128;
        int b0s = (gw - (t-1)*128)*8;
        float s = 0.f;
#pragma unroll
        for (int r = 0; r < 8; ++r) {
            const float* base = ev + ((size_t)(b0s+r)*Tn + t)*Hn + (size_t)lane*4;
            float4 v0 = *(const float4*)(base);
            float4 v1 = *(const float4*)(base + 256);
            float4 v2 = *(const float4*)(base + 512);
            s += (v0.x+v0.y+v0.z+v0.w) + (v1.x+v1.y+v1.z+v1.w) + (v2.x+v2.y+v2.z+v2.w);
        }
        s = wave_reduce(s);
        if (lane == 0) atomicAdd(ws + WS_SEV + t, s);
        return;
    }

    blk -= NB_SEV;
    {                                        // biassum, float4
        int idx = blk*256 + tid;             // 0..15359
        float4 a = *(const float4*)(bih + (size_t)idx*4);
        float4 b = *(const float4*)(bhh + (size_t)idx*4);
        float4 r4; r4.x=a.x+b.x; r4.y=a.y+b.y; r4.z=a.z+b.z; r4.w=a.w+b.w;
        *(float4*)(ws + WS_BS + (size_t)idx*4) = r4;
    }
}

// ---------------- K2: persistent fused recurrence, t=1..19 ----------------
// 256 blocks x 768 threads. Hub exchange (known-good round-0 scheme):
// blocks publish token-packed partials; block 0 polls all 256, reduces,
// broadcasts hx. Publish happens BEFORE the coefficient preload so
// propagation hides under the wih/rowsum loads.
__global__ __launch_bounds__(768) void k_steps(
    const float* __restrict__ price, const float* __restrict__ wih,
    const float* __restrict__ fcw,   const float* __restrict__ fcb,
    float* __restrict__ ws, float* __restrict__ out)
{
    __shared__ float pr[4][80];
    __shared__ float red[12];
    __shared__ float redP[4];
    __shared__ float redF[4][12];
    __shared__ float shx;

    float* Sh  = ws + WS_SH;
    float* Sev = ws + WS_SEV;
    uint64_t* part  = (uint64_t*)(ws + WS_PART);
    uint64_t* bcast = (uint64_t*)(ws + WS_BCAST);
    const float* rowsum  = ws + WS_RS;
    const float* biassum = ws + WS_BS;
    float* cbuf = ws + WS_C;

    int blk = blockIdx.x, tid = threadIdx.x;
    int lane = tid & 63, wid = tid >> 6;
    int k = tid;

    if (tid < 320) {
        int e = tid / 80, r = tid - e*80;
        pr[e][r] = price[(size_t)(blk + 256*e)*(Tn*4) + r];
    }

    float c[4];
#pragma unroll
    for (int e = 0; e < 4; ++e)
        c[e] = cbuf[(size_t)(blk + 256*e)*Hn + k];

    float fcwk = fcw[k];
    float fcb0 = fcb[0];
    float sh0  = Sh[0];

    __syncthreads();

    float hsum_prev = 0.f;
    float vout[4] = {0.f,0.f,0.f,0.f};

    for (int t = 1; t < Tn; ++t) {
        // ---- publish previous step's block partial (token t-1) ----
        if (t >= 2) {
            float v = wave_reduce(hsum_prev);
            if (lane == 0) red[wid] = v;
            __syncthreads();
            if (tid == 0) {
                float tot = 0.f;
#pragma unroll
                for (int i = 0; i < 12; ++i) tot += red[i];
                __hip_atomic_store(&part[blk], pack_tv((unsigned)(t-1), tot),
                                   __ATOMIC_RELAXED, __HIP_MEMORY_SCOPE_AGENT);
            }
        }

        // ---- preload step-t coefficients + hx-independent gate bases ----
        const float* wih_t = wih + (size_t)t*G4n*4;
        float rsv[4], base[4][4];
#pragma unroll
        for (int g = 0; g < 4; ++g) {
            int j = g*Hn + k;
            float4 wv = *(const float4*)(wih_t + (size_t)j*4);
            rsv[g]   = rowsum[t*G4n + j];
            float bs = biassum[t*G4n + j];
#pragma unroll
            for (int e = 0; e < 4; ++e) {
                base[e][g] = pr[e][t*4+0]*wv.x + pr[e][t*4+1]*wv.y
                           + pr[e][t*4+2]*wv.z + pr[e][t*4+3]*wv.w + bs;
            }
        }
        float sevt = Sev[t];

        // ---- obtain hx_t (hub) ----
        if (blk == 0) {
            if (t >= 2) {
                if (tid < 256) {
                    uint64_t u;
                    do { u = __hip_atomic_load(&part[tid], __ATOMIC_RELAXED, __HIP_MEMORY_SCOPE_AGENT); }
                    while ((unsigned)(u >> 32) != (unsigned)(t-1));
                    float pv = wave_reduce(__uint_as_float((uint32_t)u));
                    if (lane == 0) redP[wid] = pv;
                }
                __syncthreads();
                if (tid == 0) {
                    float hx = sevt + (redP[0]+redP[1]+redP[2]+redP[3]);
                    shx = hx;
                    __hip_atomic_store(bcast, pack_tv((unsigned)t, hx),
                                       __ATOMIC_RELAXED, __HIP_MEMORY_SCOPE_AGENT);
                }
            } else {
                if (tid == 0) {
                    float hx = sevt + sh0;
                    shx = hx;
                    __hip_atomic_store(bcast, pack_tv(1u, hx),
                                       __ATOMIC_RELAXED, __HIP_MEMORY_SCOPE_AGENT);
                }
            }
            __syncthreads();
        } else {
            if (tid == 0) {
                uint64_t u;
                do { u = __hip_atomic_load(bcast, __ATOMIC_RELAXED, __HIP_MEMORY_SCOPE_AGENT); }
                while ((unsigned)(u >> 32) != (unsigned)t);
                shx = __uint_as_float((uint32_t)u);
            }
            __syncthreads();
        }
        float hx = shx;

        // ---- cell update ----
        float hsum = 0.f;
#pragma unroll
        for (int e = 0; e < 4; ++e) {
            float gi = base[e][0] + hx*rsv[0];
            float gf = base[e][1] + hx*rsv[1];
            float gg = base[e][2] + hx*rsv[2];
            float go = base[e][3] + hx*rsv[3];
            float cn = sigf(gf)*c[e] + sigf(gi)*tanhfast(gg);
            c[e] = cn;
            float h = sigf(go)*tanhfast(cn);
            hsum += h;
            if (t == Tn-1) vout[e] = wave_reduce(h * fcwk);
        }
        hsum_prev = hsum;
    }

    // epilogue: out[b] = h19[b,:].fc_w + fc_b
    if (lane == 0) {
#pragma unroll
        for (int e = 0; e < 4; ++e) redF[e][wid] = vout[e];
    }
    __syncthreads();
    if (tid < 4) {
        float tot = 0.f;
#pragma unroll
        for (int i = 0; i < 12; ++i) tot += redF[tid][i];
        out[blk + 256*tid] = tot + fcb0;
    }
}

extern "C" void kernel_launch(void* const* d_in, const int* in_sizes, int n_in,
                              void* d_out, int out_size, void* d_ws, size_t ws_size,
                              hipStream_t stream)
{
    const float* price = (const float*)d_in[0];
    const float* ev    = (const float*)d_in[1];
    const float* wih   = (const float*)d_in[2];
    const float* whh   = (const float*)d_in[3];
    const float* bih   = (const float*)d_in[4];
    const float* bhh   = (const float*)d_in[5];
    const float* fcw   = (const float*)d_in[6];
    const float* fcb   = (const float*)d_in[7];
    float* out = (float*)d_out;
    float* ws  = (float*)d_ws;

    k_conv <<<NBC_TOT, 256, 0, stream>>>(ev, whh, ws);
    k_pre  <<<NB_TOTAL, 256, 0, stream>>>(price, ev, wih, whh, bih, bhh, ws);
    k_steps<<<256, 768, 0, stream>>>(price, wih, fcw, fcb, ws, out);
}

// Round 3
// 424.533 us; speedup vs baseline: 1.1194x; 1.0085x over previous
//
#include <hip/hip_runtime.h>
#include <stdint.h>

// Problem constants
#define Bsz 1024
#define Tn  20
#define Hn  768
#define G4n 3072   // 4*H

// Workspace layout (floats):
//  [0..31]      Sh[t]     (legacy, zeroed, unused)
//  [32..63]     Sev[t]    (legacy, zeroed, unused)
//  [64..575]    part[256]: uint64 {token<<32 | float bits}
//  [576..639]   bcast: uint64 {token<<32 | hx bits}
//  [640..]      rowsum[20][3072]
//  [+61440]     biassum[20][3072]
//  [+61440]     c0 handoff [1024][768]
//  then bf16 planes for the t=0 GEMM (ushort), stored in MFMA FRAGMENT ORDER:
//  chunk(rb,kb) = 64 lanes x 8 elems; elem (l,e) = plane[rb*16 + (l&15)][kb*32 + (l>>4)*8 + e]
//   evh  [64 rb][24 kb][512], evl  same      (ev[:,0,:] hi/lo)
//   wh   [144 rb][24 kb][512], wl  same      (whh[0] gates {i,g,o} hi/lo)
//  then atomic-free partial buffers (NO RMW anywhere — R3 lesson: same-line
//  far atomics serialize ~40ns each; 2432 of them was k_pre's whole 100us):
//   Shpart[768]    : per-GEMM-block h0 partials (plain stores)
//   Sevpart[19*128]: per-wave ev partials (plain stores)
#define WS_SH    0
#define WS_SEV   32
#define WS_PART  64
#define WS_BCAST 576
#define WS_RS    640
#define WS_BS    62080
#define WS_C     123520
#define WS_EVH   909952
#define WS_EVL   1303168
#define WS_WH    1696384
#define WS_WL    2581120
#define WS_SHP   3465856
#define WS_SEVP  3466624

// k_conv blocks: 512 ev (2 rows each) + 1152 whh (2 plane-rows each) + 3 zero
#define NBC_EV   512
#define NBC_W    1152
#define NBC_Z    3
#define NBC_TOT  (NBC_EV + NBC_W + NBC_Z)

// k_pre blocks
#define NB_GEMM   768    // 16 bt x 48 kt, 64x16 tile x 3 gates
#define NB_ROWSUM 1824   // 19*3072 rows / (4 waves * 8 rows)
#define NB_SEV    608    // 19*1024 rows / (4 waves * 8 rows)
#define NB_BIAS   60     // 61440 floats / (256 thr * float4)
#define NB_TOTAL  (NB_GEMM + NB_ROWSUM + NB_SEV + NB_BIAS)

typedef float  floatx4 __attribute__((ext_vector_type(4)));
typedef short  bfrag8  __attribute__((ext_vector_type(8)));

__device__ __forceinline__ float wave_reduce(float v){
#pragma unroll
    for (int o = 32; o > 0; o >>= 1) v += __shfl_down(v, o, 64);
    return v;
}
__device__ __forceinline__ float sigf(float x){ return 1.0f/(1.0f+__expf(-x)); }
__device__ __forceinline__ float tanhfast(float x){ return 2.0f/(1.0f+__expf(-2.0f*x)) - 1.0f; }
__device__ __forceinline__ unsigned short f2bf(float f){
    uint32_t u = __float_as_uint(f);
    return (unsigned short)((u + 0x7fffu + ((u>>16)&1u)) >> 16);
}
__device__ __forceinline__ float bf2f(unsigned short h){ return __uint_as_float(((uint32_t)h)<<16); }
__device__ __forceinline__ uint64_t pack_tv(unsigned t, float v){
    return ((uint64_t)t << 32) | (uint64_t)__float_as_uint(v);
}

// ---------------- K0: one-time bf16 hi/lo conversion into fragment-order planes ----------------
__global__ __launch_bounds__(256) void k_conv(
    const float* __restrict__ ev, const float* __restrict__ whh,
    float* __restrict__ ws)
{
    int bid = blockIdx.x, tid = threadIdx.x;
    if (bid < NBC_EV + NBC_W) {
        if (tid >= 192) return;
        int r = tid / 96;                 // which of the 2 rows this block covers
        int i = (tid - r*96) * 8;         // element offset 0..760
        const float* src;
        unsigned short *dh, *dl;
        int prow;                         // plane row index
        if (bid < NBC_EV) {
            prow = bid*2 + r;             // ev row b (t=0 slice)
            src = ev + (size_t)prow*(Tn*Hn) + i;
            dh = (unsigned short*)(ws + WS_EVH);
            dl = (unsigned short*)(ws + WS_EVL);
        } else {
            int p = (bid - NBC_EV)*2 + r;           // plane row 0..2303
            int gsel = p / Hn;                      // 0,1,2
            int ga = (gsel==0) ? 0 : (gsel==1 ? 2 : 3);  // gates i,g,o
            int j = ga*Hn + (p - gsel*Hn);          // whh[0] row
            prow = p;
            src = whh + (size_t)j*Hn + i;
            dh = (unsigned short*)(ws + WS_WH);
            dl = (unsigned short*)(ws + WS_WL);
        }
        // fragment-order destination: chunk(rb,kb), lane q*16+col, elem e
        int rb = prow >> 4, col = prow & 15;
        int kb = i >> 5, q = (i >> 3) & 3;
        size_t base = (((size_t)(rb*24 + kb))*64 + q*16 + col) * 8;

        float4 v0 = *(const float4*)src;
        float4 v1 = *(const float4*)(src+4);
        float f[8] = {v0.x,v0.y,v0.z,v0.w,v1.x,v1.y,v1.z,v1.w};
        bfrag8 hv, lv;
#pragma unroll
        for (int qq = 0; qq < 8; ++qq) {
            unsigned short hb = f2bf(f[qq]);
            hv[qq] = (short)hb;
            lv[qq] = (short)f2bf(f[qq] - bf2f(hb));
        }
        *(bfrag8*)(dh + base) = hv;
        *(bfrag8*)(dl + base) = lv;
    } else {
        int idx = (bid - NBC_EV - NBC_W)*256 + tid;
        if (idx < 640) ws[idx] = 0.0f;    // Sh, Sev, part tokens, bcast token
    }
}

// ---------------- K1 (merged): t=0 GEMM + rowsums + Sev + biassums ----------------
// ZERO atomics: all reductions end in private plain-store slots.
__global__ __launch_bounds__(256) void k_pre(
    const float* __restrict__ price, const float* __restrict__ ev,
    const float* __restrict__ wih,   const float* __restrict__ whh,
    const float* __restrict__ bih,   const float* __restrict__ bhh,
    float* __restrict__ ws)
{
    __shared__ float redk[4];
    int blk = blockIdx.x, tid = threadIdx.x;
    int lane = tid & 63, wid = tid >> 6;

    if (blk < NB_GEMM) {
        // ----- t=0 GEMM, 3 live gates {i,g,o}, bf16x3, fragment-order coalesced loads -----
        float* cbuf = ws + WS_C;
        int bt = blk / 48, kt = blk % 48;
        int b0 = bt*64, k0 = kt*16;
        int w = wid, q = lane >> 4, col = lane & 15;

        const unsigned short* evh = (const unsigned short*)(ws + WS_EVH);
        const unsigned short* evl = (const unsigned short*)(ws + WS_EVL);
        const unsigned short* wh  = (const unsigned short*)(ws + WS_WH);
        const unsigned short* wl  = (const unsigned short*)(ws + WS_WL);

        int rb_a = bt*4 + w;
        const unsigned short* pah = evh + (size_t)rb_a*24*512 + (size_t)lane*8;
        const unsigned short* pal = evl + (size_t)rb_a*24*512 + (size_t)lane*8;
        const unsigned short* pb0h = wh + (size_t)(  0 + kt)*24*512 + (size_t)lane*8; // gate i
        const unsigned short* pb0l = wl + (size_t)(  0 + kt)*24*512 + (size_t)lane*8;
        const unsigned short* pb1h = wh + (size_t)( 48 + kt)*24*512 + (size_t)lane*8; // gate g
        const unsigned short* pb1l = wl + (size_t)( 48 + kt)*24*512 + (size_t)lane*8;
        const unsigned short* pb2h = wh + (size_t)( 96 + kt)*24*512 + (size_t)lane*8; // gate o
        const unsigned short* pb2l = wl + (size_t)( 96 + kt)*24*512 + (size_t)lane*8;

        floatx4 acc0 = (floatx4){0.f,0.f,0.f,0.f};
        floatx4 acc1 = (floatx4){0.f,0.f,0.f,0.f};
        floatx4 acc2 = (floatx4){0.f,0.f,0.f,0.f};

#pragma unroll 4
        for (int kb = 0; kb < 24; ++kb) {
            int off = kb*512;
            bfrag8 ah  = *(const bfrag8*)(pah  + off);
            bfrag8 al  = *(const bfrag8*)(pal  + off);
            bfrag8 b0h = *(const bfrag8*)(pb0h + off);
            bfrag8 b0l = *(const bfrag8*)(pb0l + off);
            acc0 = __builtin_amdgcn_mfma_f32_16x16x32_bf16(ah, b0h, acc0, 0,0,0);
            acc0 = __builtin_amdgcn_mfma_f32_16x16x32_bf16(ah, b0l, acc0, 0,0,0);
            acc0 = __builtin_amdgcn_mfma_f32_16x16x32_bf16(al, b0h, acc0, 0,0,0);
            bfrag8 b1h = *(const bfrag8*)(pb1h + off);
            bfrag8 b1l = *(const bfrag8*)(pb1l + off);
            acc1 = __builtin_amdgcn_mfma_f32_16x16x32_bf16(ah, b1h, acc1, 0,0,0);
            acc1 = __builtin_amdgcn_mfma_f32_16x16x32_bf16(ah, b1l, acc1, 0,0,0);
            acc1 = __builtin_amdgcn_mfma_f32_16x16x32_bf16(al, b1h, acc1, 0,0,0);
            bfrag8 b2h = *(const bfrag8*)(pb2h + off);
            bfrag8 b2l = *(const bfrag8*)(pb2l + off);
            acc2 = __builtin_amdgcn_mfma_f32_16x16x32_bf16(ah, b2h, acc2, 0,0,0);
            acc2 = __builtin_amdgcn_mfma_f32_16x16x32_bf16(ah, b2l, acc2, 0,0,0);
            acc2 = __builtin_amdgcn_mfma_f32_16x16x32_bf16(al, b2h, acc2, 0,0,0);
        }

        // epilogue (weights/bias hoisted out of the r loop — r-independent)
        int j0 = 0*Hn + k0 + col;
        int j1 = 2*Hn + k0 + col;
        int j2 = 3*Hn + k0 + col;
        float4 w0 = *(const float4*)(wih + (size_t)j0*4);
        float4 w1 = *(const float4*)(wih + (size_t)j1*4);
        float4 w2 = *(const float4*)(wih + (size_t)j2*4);
        float bb0 = bih[j0] + bhh[j0];
        float bb1 = bih[j1] + bhh[j1];
        float bb2 = bih[j2] + bhh[j2];

        float hsum = 0.f;
#pragma unroll
        for (int r = 0; r < 4; ++r) {
            int b = b0 + w*16 + q*4 + r;
            float4 xv = *(const float4*)(price + (size_t)b*(Tn*4));
            float gi = acc0[r] + xv.x*w0.x + xv.y*w0.y + xv.z*w0.z + xv.w*w0.w + bb0;
            float gg = acc1[r] + xv.x*w1.x + xv.y*w1.y + xv.z*w1.z + xv.w*w1.w + bb1;
            float go = acc2[r] + xv.x*w2.x + xv.y*w2.y + xv.z*w2.z + xv.w*w2.w + bb2;
            float c0 = sigf(gi) * tanhfast(gg);
            float h0 = sigf(go) * tanhfast(c0);
            cbuf[(size_t)b*Hn + k0 + col] = c0;
            hsum += h0;
        }
        hsum = wave_reduce(hsum);
        if (lane == 0) redk[w] = hsum;
        __syncthreads();
        if (tid == 0)
            ws[WS_SHP + blk] = redk[0]+redk[1]+redk[2]+redk[3];   // plain store, no RMW
        return;
    }

    blk -= NB_GEMM;
    if (blk < NB_ROWSUM) {                   // whh row sums, t=1..19, 8 rows/wave
        int gw = blk*4 + wid;
        int t  = 1 + gw/384;
        int j0 = (gw - (t-1)*384)*8;
        const float* base = whh + ((size_t)t*G4n + j0)*Hn + (size_t)lane*4;
        float s[8];
#pragma unroll
        for (int r = 0; r < 8; ++r) {
            float4 v0 = *(const float4*)(base + (size_t)r*Hn);
            float4 v1 = *(const float4*)(base + (size_t)r*Hn + 256);
            float4 v2 = *(const float4*)(base + (size_t)r*Hn + 512);
            s[r] = (v0.x+v0.y+v0.z+v0.w) + (v1.x+v1.y+v1.z+v1.w) + (v2.x+v2.y+v2.z+v2.w);
        }
        float* rowsum = ws + WS_RS;
#pragma unroll
        for (int r = 0; r < 8; ++r) {
            float rs = wave_reduce(s[r]);
            if (lane == 0) rowsum[(size_t)t*G4n + j0 + r] = rs;
        }
        return;
    }

    blk -= NB_ROWSUM;
    if (blk < NB_SEV) {                      // Sev partials, 8 b-rows/wave, private slots
        int gw = blk*4 + wid;                // 0..2431
        int t   = 1 + gw/128;
        int b0s = (gw - (t-1)*128)*8;
        float s = 0.f;
#pragma unroll
        for (int r = 0; r < 8; ++r) {
            const float* base = ev + ((size_t)(b0s+r)*Tn + t)*Hn + (size_t)lane*4;
            float4 v0 = *(const float4*)(base);
            float4 v1 = *(const float4*)(base + 256);
            float4 v2 = *(const float4*)(base + 512);
            s += (v0.x+v0.y+v0.z+v0.w) + (v1.x+v1.y+v1.z+v1.w) + (v2.x+v2.y+v2.z+v2.w);
        }
        s = wave_reduce(s);
        if (lane == 0) ws[WS_SEVP + gw] = s;  // plain store, no RMW
        return;
    }

    blk -= NB_SEV;
    {                                        // biassum, float4
        int idx = blk*256 + tid;             // 0..15359
        float4 a = *(const float4*)(bih + (size_t)idx*4);
        float4 b = *(const float4*)(bhh + (size_t)idx*4);
        float4 r4; r4.x=a.x+b.x; r4.y=a.y+b.y; r4.z=a.z+b.z; r4.w=a.w+b.w;
        *(float4*)(ws + WS_BS + (size_t)idx*4) = r4;
    }
}

// ---------------- K2: persistent fused recurrence, t=1..19 ----------------
// 257 blocks x 768 threads. Block 256 = DEDICATED 1-wave hub: no cell work,
// spins on the 256 partials full-time (4 slots/lane), reduces, adds the
// Sev[t] total (reduced from Sevpart in-loop, hidden under worker compute),
// broadcasts hx. Workers are uniform: publish -> preload -> poll bcast.
__global__ __launch_bounds__(768) void k_steps(
    const float* __restrict__ price, const float* __restrict__ wih,
    const float* __restrict__ fcw,   const float* __restrict__ fcb,
    float* __restrict__ ws, float* __restrict__ out)
{
    __shared__ float pr[4][80];
    __shared__ float red[12];
    __shared__ float redF[4][12];
    __shared__ float shx;

    uint64_t* part  = (uint64_t*)(ws + WS_PART);
    uint64_t* bcast = (uint64_t*)(ws + WS_BCAST);
    const float* rowsum  = ws + WS_RS;
    const float* biassum = ws + WS_BS;
    float* cbuf = ws + WS_C;

    int blk = blockIdx.x, tid = threadIdx.x;

    if (blk == 256) {
        // ---------------- hub ----------------
        if (tid >= 64) return;
        int lane = tid;
        const float* shp  = ws + WS_SHP;
        const float* sevp = ws + WS_SEVP;

        // Sh0 = sum of 768 GEMM-block partials
        float s = 0.f;
#pragma unroll
        for (int i = 0; i < 12; ++i) s += shp[lane + 64*i];
        s = wave_reduce(s);                       // valid on lane 0

        // t=1: hx = Sev[1] + Sh0
        {
            float sv = sevp[lane] + sevp[64 + lane];
            sv = wave_reduce(sv);
            if (lane == 0)
                __hip_atomic_store(bcast, pack_tv(1u, sv + s),
                                   __ATOMIC_RELAXED, __HIP_MEMORY_SCOPE_AGENT);
        }

        for (int t = 2; t < Tn; ++t) {
            // Sev[t] total (independent of the poll; hidden under worker compute)
            float sv = sevp[(t-1)*128 + lane] + sevp[(t-1)*128 + 64 + lane];
            sv = wave_reduce(sv);

            // poll all 256 partials for token t-1 (4 slots per lane)
            unsigned want = (unsigned)(t-1);
            uint64_t u0,u1,u2,u3;
            for (;;) {
                u0 = __hip_atomic_load(&part[lane*4+0], __ATOMIC_RELAXED, __HIP_MEMORY_SCOPE_AGENT);
                u1 = __hip_atomic_load(&part[lane*4+1], __ATOMIC_RELAXED, __HIP_MEMORY_SCOPE_AGENT);
                u2 = __hip_atomic_load(&part[lane*4+2], __ATOMIC_RELAXED, __HIP_MEMORY_SCOPE_AGENT);
                u3 = __hip_atomic_load(&part[lane*4+3], __ATOMIC_RELAXED, __HIP_MEMORY_SCOPE_AGENT);
                if ((unsigned)(u0>>32)==want && (unsigned)(u1>>32)==want &&
                    (unsigned)(u2>>32)==want && (unsigned)(u3>>32)==want) break;
            }
            float p = __uint_as_float((uint32_t)u0) + __uint_as_float((uint32_t)u1)
                    + __uint_as_float((uint32_t)u2) + __uint_as_float((uint32_t)u3);
            p = wave_reduce(p);
            if (lane == 0)
                __hip_atomic_store(bcast, pack_tv((unsigned)t, sv + p),
                                   __ATOMIC_RELAXED, __HIP_MEMORY_SCOPE_AGENT);
        }
        return;
    }

    // ---------------- worker ----------------
    int lane = tid & 63, wid = tid >> 6;
    int k = tid;

    if (tid < 320) {
        int e = tid / 80, r = tid - e*80;
        pr[e][r] = price[(size_t)(blk + 256*e)*(Tn*4) + r];
    }

    float c[4];
#pragma unroll
    for (int e = 0; e < 4; ++e)
        c[e] = cbuf[(size_t)(blk + 256*e)*Hn + k];

    float fcwk = fcw[k];
    float fcb0 = fcb[0];

    __syncthreads();

    float hsum_prev = 0.f;
    float vout[4] = {0.f,0.f,0.f,0.f};

    for (int t = 1; t < Tn; ++t) {
        // ---- publish previous step's block partial (token t-1) ----
        if (t >= 2) {
            float v = wave_reduce(hsum_prev);
            if (lane == 0) red[wid] = v;
            __syncthreads();
            if (tid == 0) {
                float tot = 0.f;
#pragma unroll
                for (int i = 0; i < 12; ++i) tot += red[i];
                __hip_atomic_store(&part[blk], pack_tv((unsigned)(t-1), tot),
                                   __ATOMIC_RELAXED, __HIP_MEMORY_SCOPE_AGENT);
            }
        }

        // ---- preload step-t coefficients + hx-independent gate bases ----
        const float* wih_t = wih + (size_t)t*G4n*4;
        float rsv[4], base[4][4];
#pragma unroll
        for (int g = 0; g < 4; ++g) {
            int j = g*Hn + k;
            float4 wv = *(const float4*)(wih_t + (size_t)j*4);
            rsv[g]   = rowsum[t*G4n + j];
            float bs = biassum[t*G4n + j];
#pragma unroll
            for (int e = 0; e < 4; ++e) {
                base[e][g] = pr[e][t*4+0]*wv.x + pr[e][t*4+1]*wv.y
                           + pr[e][t*4+2]*wv.z + pr[e][t*4+3]*wv.w + bs;
            }
        }

        // ---- obtain hx_t from hub broadcast ----
        if (tid == 0) {
            uint64_t u;
            do { u = __hip_atomic_load(bcast, __ATOMIC_RELAXED, __HIP_MEMORY_SCOPE_AGENT); }
            while ((unsigned)(u >> 32) != (unsigned)t);
            shx = __uint_as_float((uint32_t)u);
        }
        __syncthreads();
        float hx = shx;

        // ---- cell update ----
        float hsum = 0.f;
#pragma unroll
        for (int e = 0; e < 4; ++e) {
            float gi = base[e][0] + hx*rsv[0];
            float gf = base[e][1] + hx*rsv[1];
            float gg = base[e][2] + hx*rsv[2];
            float go = base[e][3] + hx*rsv[3];
            float cn = sigf(gf)*c[e] + sigf(gi)*tanhfast(gg);
            c[e] = cn;
            float h = sigf(go)*tanhfast(cn);
            hsum += h;
            if (t == Tn-1) vout[e] = wave_reduce(h * fcwk);
        }
        hsum_prev = hsum;
    }

    // epilogue: out[b] = h19[b,:].fc_w + fc_b
    if (lane == 0) {
#pragma unroll
        for (int e = 0; e < 4; ++e) redF[e][wid] = vout[e];
    }
    __syncthreads();
    if (tid < 4) {
        float tot = 0.f;
#pragma unroll
        for (int i = 0; i < 12; ++i) tot += redF[tid][i];
        out[blk + 256*tid] = tot + fcb0;
    }
}

extern "C" void kernel_launch(void* const* d_in, const int* in_sizes, int n_in,
                              void* d_out, int out_size, void* d_ws, size_t ws_size,
                              hipStream_t stream)
{
    const float* price = (const float*)d_in[0];
    const float* ev    = (const float*)d_in[1];
    const float* wih   = (const float*)d_in[2];
    const float* whh   = (const float*)d_in[3];
    const float* bih   = (const float*)d_in[4];
    const float* bhh   = (const float*)d_in[5];
    const float* fcw   = (const float*)d_in[6];
    const float* fcb   = (const float*)d_in[7];
    float* out = (float*)d_out;
    float* ws  = (float*)d_ws;

    k_conv <<<NBC_TOT, 256, 0, stream>>>(ev, whh, ws);
    k_pre  <<<NB_TOTAL, 256, 0, stream>>>(price, ev, wih, whh, bih, bhh, ws);
    k_steps<<<257, 768, 0, stream>>>(price, wih, fcw, fcb, ws, out);
}